// Round 5
// baseline (408.130 us; speedup 1.0000x reference)
//
#include <hip/hip_runtime.h>

// GCN layer: out = relu(segment_sum(edge_val * (x@W + b)[edge_col] -> edge_row))
// N=100000 nodes, E=1600000 edges, 256 -> 128 features, fp32 in/out.
//
// Round 11: make the aggregate gather L2-RESIDENT. r10 rocprof: aggregate
// 63us, FETCH 185MB, VALU 31% -> bound by L2-miss path (410MB logical
// gather vs 4MB per-XCD L2 over a 25.6MB table, ~55% hit). Fix: split the
// 128 features into 8 slices of 16; per-slice support = 100K x 32B = 3.2MB
// -> fits one XCD's L2. slice = blockIdx&7 rides the round-robin block->XCD
// dispatch so slice s stays on XCD s (perf heuristic only; correctness
// independent). GEMM now writes support SLICE-MAJOR [8][N][16] so each
// slice's footprint is dense lines. Aggregate block = 64 nodes x 4 lanes,
// 8B gathers, float4 out. Price: packed/row_start re-read once per slice
// (~106MB sequential stream) -- cheaper than random L2 misses.
// gemm core (r9 global_load_lds+dbuf+swizzle), bhist/bscan/bin/place (r10)
// unchanged.

constexpr int kNodes = 100000;
constexpr int kEdges = 1600000;
constexpr int kInF   = 256;
constexpr int kOutF  = 128;
constexpr int kTiles = kNodes / 16;                 // 6250
constexpr int kBucketBlocks = 800;                  // 800*256*8 >= E
constexpr int kGemmBlocks = 1250;                   // 5 tiles per block

constexpr int kNB = 256;                            // coarse buckets
constexpr int kRB = 391;                            // rows per bucket (256*391 >= N)
constexpr int kCap = 7424;                          // LDS-staged edges per bucket (58KB)

constexpr int kAggTiles = (kNodes + 63) / 64;       // 1563 node tiles (64 nodes each)

typedef __attribute__((ext_vector_type(8))) short short8;
typedef __attribute__((ext_vector_type(8))) unsigned short ush8;
typedef __attribute__((ext_vector_type(4))) unsigned short ush4;
typedef __attribute__((ext_vector_type(4))) float floatx4;

__device__ inline unsigned short f2bf_rne(float f) {
    unsigned int u = __float_as_uint(f);
    unsigned int r = u + 0x7FFFu + ((u >> 16) & 1u);
    return (unsigned short)(r >> 16);
}
__device__ inline float bf2f(unsigned short h) {
    return __uint_as_float(((unsigned int)h) << 16);
}

// 8 fp32 -> 8 bf16 (RNE) via 4x v_cvt_pk_bf16_f32.
__device__ inline short8 cvt8_bf16(const float4 a, const float4 b) {
    union { short8 s; unsigned int u[4]; } r;
    asm("v_cvt_pk_bf16_f32 %0, %1, %2" : "=v"(r.u[0]) : "v"(a.x), "v"(a.y));
    asm("v_cvt_pk_bf16_f32 %0, %1, %2" : "=v"(r.u[1]) : "v"(a.z), "v"(a.w));
    asm("v_cvt_pk_bf16_f32 %0, %1, %2" : "=v"(r.u[2]) : "v"(b.x), "v"(b.y));
    asm("v_cvt_pk_bf16_f32 %0, %1, %2" : "=v"(r.u[3]) : "v"(b.z), "v"(b.w));
    return r.s;
}

// async 16B global->LDS (dest = wave-uniform base + lane*16)
__device__ inline void gload_lds16(const void* g, void* l) {
    __builtin_amdgcn_global_load_lds(
        (const __attribute__((address_space(1))) unsigned int*)g,
        (__attribute__((address_space(3))) unsigned int*)l,
        16, 0, 0);
}

// ---------------------------------------------------------------------------
// GEMM: support_bf[slice][N][16] = bf16(x[N][256] @ W[256][128] + b)
// (r9 core; epilogue writes slice-major: col -> slice=col>>4, f=col&15)
// ---------------------------------------------------------------------------
__global__ __launch_bounds__(256) void gcn_gemm(const float* __restrict__ x,
                                                const float* __restrict__ W,
                                                const float* __restrict__ b,
                                                unsigned short* __restrict__ support) {
    __shared__ __align__(16) float lbuf[2][4096];   // 2 x 16KB

    const int lane = threadIdx.x & 63;
    const int wv   = threadIdx.x >> 6;
    const int rowl = lane & 15;
    const int quad = lane >> 4;
    const int colbase = wv * 32;

    short8 bfrag[2][8];
#pragma unroll
    for (int ct = 0; ct < 2; ++ct) {
        const int col = colbase + ct * 16 + rowl;
#pragma unroll
        for (int kc = 0; kc < 8; ++kc) {
            const int kb = kc * 32 + quad * 8;
            short8 f;
#pragma unroll
            for (int j = 0; j < 8; ++j)
                f[j] = (short)f2bf_rne(W[(size_t)(kb + j) * kOutF + col]);
            bfrag[ct][kc] = f;
        }
    }
    const float bias0 = b[colbase + rowl];
    const float bias1 = b[colbase + 16 + rowl];

    // slice-major bases for this wave's two 16-col slices
    unsigned short* s0p = support + (size_t)(wv * 2)     * kNodes * 16 + rowl;
    unsigned short* s1p = support + (size_t)(wv * 2 + 1) * kNodes * 16 + rowl;

    const int G = gridDim.x;
    int t = blockIdx.x;

#define GEMM_STAGE(buf_, tile_)                                                   \
    do {                                                                          \
        const float* tb_ = x + (size_t)(tile_) * 16 * kInF;                       \
        _Pragma("unroll")                                                         \
        for (int i_ = 0; i_ < 4; ++i_) {                                          \
            const int row_ = i_ * 4 + wv;                                         \
            gload_lds16(tb_ + (size_t)row_ * kInF + ((lane ^ (row_ & 7)) << 2),   \
                        &lbuf[buf_][row_ << 8]);                                  \
        }                                                                         \
    } while (0)

    if (t < kTiles) GEMM_STAGE(0, t);
    int cur = 0;

    for (; t < kTiles; t += G) {
        const int tn = t + G;
        asm volatile("s_waitcnt vmcnt(0)" ::: "memory");
        __syncthreads();
        if (tn < kTiles) GEMM_STAGE(cur ^ 1, tn);

        const int r0 = t * 16;
        const float* base = &lbuf[cur][rowl << 8];
        const int rsw = rowl & 7;
        floatx4 acc0 = {0.f, 0.f, 0.f, 0.f};
        floatx4 acc1 = {0.f, 0.f, 0.f, 0.f};
#pragma unroll
        for (int kc = 0; kc < 8; ++kc) {
            const int g0 = (kc << 3) + (quad << 1);
            const float4 v0 = *reinterpret_cast<const float4*>(base + ((g0 ^ rsw) << 2));
            const float4 v1 = *reinterpret_cast<const float4*>(base + (((g0 + 1) ^ rsw) << 2));
            const short8 a = cvt8_bf16(v0, v1);
            acc0 = __builtin_amdgcn_mfma_f32_16x16x32_bf16(a, bfrag[0][kc], acc0, 0, 0, 0);
            acc1 = __builtin_amdgcn_mfma_f32_16x16x32_bf16(a, bfrag[1][kc], acc1, 0, 0, 0);
        }
#pragma unroll
        for (int reg = 0; reg < 4; ++reg) {
            const size_t node = (size_t)(r0 + quad * 4 + reg);
            s0p[node * 16] = f2bf_rne(acc0[reg] + bias0);
            s1p[node * 16] = f2bf_rne(acc1[reg] + bias1);
        }
        cur ^= 1;
    }
#undef GEMM_STAGE
}

// ---------------------------------------------------------------------------
// Bucket histogram: per-block LDS hist over 256 buckets. (r10, unchanged)
// ---------------------------------------------------------------------------
__global__ __launch_bounds__(256) void gcn_bhist(const int* __restrict__ erow,
                                                 int* __restrict__ bucket_tot) {
    __shared__ int cnt[kNB];
    cnt[threadIdx.x] = 0;
    __syncthreads();
    const int stride = gridDim.x * blockDim.x;
    for (int e = blockIdx.x * blockDim.x + threadIdx.x; e < kEdges; e += stride)
        atomicAdd(&cnt[(unsigned int)erow[e] / (unsigned int)kRB], 1);
    __syncthreads();
    const int c = cnt[threadIdx.x];
    if (c) atomicAdd(&bucket_tot[threadIdx.x], c);
}

// ---------------------------------------------------------------------------
// Bucket scan: one block, exclusive scan of 256 totals. (r10, unchanged)
// ---------------------------------------------------------------------------
__global__ __launch_bounds__(256) void gcn_bscan(const int* __restrict__ bucket_tot,
                                                 int* __restrict__ bucket_base,
                                                 int* __restrict__ bucket_cursor,
                                                 int* __restrict__ row_start) {
    __shared__ int s[256];
    const int v = bucket_tot[threadIdx.x];
    s[threadIdx.x] = v;
    __syncthreads();
#pragma unroll
    for (int off = 1; off < 256; off <<= 1) {
        const int t = (threadIdx.x >= off) ? s[threadIdx.x - off] : 0;
        __syncthreads();
        s[threadIdx.x] += t;
        __syncthreads();
    }
    const int excl = s[threadIdx.x] - v;
    bucket_base[threadIdx.x]   = excl;
    bucket_cursor[threadIdx.x] = excl;
    if (threadIdx.x == 255) {
        bucket_base[256]   = kEdges;
        row_start[kNodes]  = kEdges;
    }
}

// ---------------------------------------------------------------------------
// Phase A: bin edges into 256 coarse buckets, write-combined. (unchanged)
// packed.x = (row_local<<17) | col. packed.y = val.
// ---------------------------------------------------------------------------
__global__ __launch_bounds__(256) void gcn_bin(const int* __restrict__ erow,
                                               const int* __restrict__ ecol,
                                               const float* __restrict__ eval,
                                               int* __restrict__ bucket_cursor,
                                               int2* __restrict__ packed) {
    __shared__ int cnt[kNB];
    __shared__ int base[kNB];
    __shared__ int rk[kNB];
    const int T   = kBucketBlocks * 256;
    const int tid = blockIdx.x * 256 + threadIdx.x;

    cnt[threadIdx.x] = 0;
    rk[threadIdx.x]  = 0;

    int bk[8], pk[8], vb[8];
    bool ok[8];
#pragma unroll
    for (int i = 0; i < 8; ++i) {
        const int e = tid + i * T;
        ok[i] = (e < kEdges);
        const int r = ok[i] ? erow[e] : 0;
        const int c = ok[i] ? ecol[e] : 0;
        const float v = ok[i] ? eval[e] : 0.f;
        const unsigned int b = (unsigned int)r / (unsigned int)kRB;
        bk[i] = (int)b;
        pk[i] = ((r - (int)b * kRB) << 17) | c;
        vb[i] = __float_as_int(v);
    }
    __syncthreads();
#pragma unroll
    for (int i = 0; i < 8; ++i)
        if (ok[i]) atomicAdd(&cnt[bk[i]], 1);
    __syncthreads();
    const int c = cnt[threadIdx.x];
    base[threadIdx.x] = c ? atomicAdd(&bucket_cursor[threadIdx.x], c) : 0;
    __syncthreads();
#pragma unroll
    for (int i = 0; i < 8; ++i) {
        if (ok[i]) {
            const int r = atomicAdd(&rk[bk[i]], 1);
            packed[base[bk[i]] + r] = make_int2(pk[i], vb[i]);
        }
    }
}

// ---------------------------------------------------------------------------
// Phase B: per-bucket place, all bookkeeping in LDS. (r10, unchanged)
// ---------------------------------------------------------------------------
__global__ __launch_bounds__(256) void gcn_place(const int* __restrict__ bucket_base,
                                                 int* __restrict__ row_start,
                                                 int2* __restrict__ packed) {
    __shared__ int2 st[kCap];       // 59,392 B
    __shared__ int  s[512];         //  2,048 B
    __shared__ int  rcur[kRB + 1];  //  1,568 B
    const int bk = blockIdx.x;
    const int r0 = bk * kRB;
    const int r1 = min(r0 + kRB, kNodes);
    const int NR = r1 - r0;
    if (NR <= 0) return;
    const int bb = bucket_base[bk];
    const int s1 = bucket_base[bk + 1];
    const int size   = s1 - bb;
    const int staged = min(size, kCap);
    const int tid = threadIdx.x;

    s[tid] = 0;
    s[tid + 256] = 0;
    __syncthreads();

    for (int i = tid; i < staged; i += 256) {
        const int2 p = packed[bb + i];
        st[i] = p;
        atomicAdd(&s[p.x >> 17], 1);
    }
    int2 tail[8];
    int  nt = 0;
    for (int i = kCap + tid; i < size; i += 256) {
        if (nt < 8) {
            tail[nt] = packed[bb + i];
            atomicAdd(&s[tail[nt].x >> 17], 1);
            ++nt;
        }
    }
    __syncthreads();

    const int i0 = tid, i1 = tid + 256;
#pragma unroll
    for (int off = 1; off < 512; off <<= 1) {
        const int v0 = (i0 >= off) ? s[i0 - off] : 0;
        const int v1 = (i1 >= off) ? s[i1 - off] : 0;
        __syncthreads();
        s[i0] += v0;
        s[i1] += v1;
        __syncthreads();
    }

    for (int i = tid; i < NR; i += 256) {
        const int excl = i ? s[i - 1] : 0;
        row_start[r0 + i] = bb + excl;
        rcur[i] = excl;
    }
    __syncthreads();

    for (int i = tid; i < staged; i += 256) {
        const int2 p  = st[i];
        const int pos = bb + atomicAdd(&rcur[p.x >> 17], 1);
        packed[pos] = make_int2(p.x & 0x1FFFF, p.y);
    }
#pragma unroll
    for (int t = 0; t < 8; ++t) {
        if (t < nt) {
            const int2 p  = tail[t];
            const int pos = bb + atomicAdd(&rcur[p.x >> 17], 1);
            packed[pos] = make_int2(p.x & 0x1FFFF, p.y);
        }
    }
}

// ---------------------------------------------------------------------------
// Aggregate + ReLU, feature-sliced for L2 residency:
// slice = blockIdx&7 (rides round-robin block->XCD dispatch), tile = blockIdx>>3.
// Block = 64 nodes x 4 lanes; lane gathers ush4 (4 bf16 = 8B) per edge from
// the slice's dense 3.2MB table; accumulates float4; one float4 store.
// ---------------------------------------------------------------------------
__global__ __launch_bounds__(256) void gcn_aggregate(const int* __restrict__ row_start,
                                                     const int2* __restrict__ packed,
                                                     const unsigned short* __restrict__ support,
                                                     float* __restrict__ out) {
    const int slice = blockIdx.x & 7;
    const int tile  = blockIdx.x >> 3;
    const int n  = tile * 64 + (threadIdx.x >> 2);
    const int lq = threadIdx.x & 3;                 // feature quad within slice
    if (n >= kNodes) return;
    const unsigned short* sb = support + (size_t)slice * kNodes * 16 + lq * 4;
    const int s0 = row_start[n];
    const int s1 = row_start[n + 1];
    float a0 = 0.f, a1 = 0.f, a2 = 0.f, a3 = 0.f;

    int i = s0;
    for (; i + 3 < s1; i += 4) {
        const int2 p0 = packed[i];
        const int2 p1 = packed[i + 1];
        const int2 p2 = packed[i + 2];
        const int2 p3 = packed[i + 3];
        const ush4 g0 = *reinterpret_cast<const ush4*>(sb + (size_t)p0.x * 16);
        const ush4 g1 = *reinterpret_cast<const ush4*>(sb + (size_t)p1.x * 16);
        const ush4 g2 = *reinterpret_cast<const ush4*>(sb + (size_t)p2.x * 16);
        const ush4 g3 = *reinterpret_cast<const ush4*>(sb + (size_t)p3.x * 16);
        const float v0 = __int_as_float(p0.y), v1 = __int_as_float(p1.y);
        const float v2 = __int_as_float(p2.y), v3 = __int_as_float(p3.y);
        a0 += v0 * bf2f(g0[0]) + v1 * bf2f(g1[0]) + v2 * bf2f(g2[0]) + v3 * bf2f(g3[0]);
        a1 += v0 * bf2f(g0[1]) + v1 * bf2f(g1[1]) + v2 * bf2f(g2[1]) + v3 * bf2f(g3[1]);
        a2 += v0 * bf2f(g0[2]) + v1 * bf2f(g1[2]) + v2 * bf2f(g2[2]) + v3 * bf2f(g3[2]);
        a3 += v0 * bf2f(g0[3]) + v1 * bf2f(g1[3]) + v2 * bf2f(g2[3]) + v3 * bf2f(g3[3]);
    }
    for (; i < s1; ++i) {
        const int2 p = packed[i];
        const float v = __int_as_float(p.y);
        const ush4 g = *reinterpret_cast<const ush4*>(sb + (size_t)p.x * 16);
        a0 += v * bf2f(g[0]);
        a1 += v * bf2f(g[1]);
        a2 += v * bf2f(g[2]);
        a3 += v * bf2f(g[3]);
    }

    const float4 o = make_float4(fmaxf(a0, 0.f), fmaxf(a1, 0.f),
                                 fmaxf(a2, 0.f), fmaxf(a3, 0.f));
    *reinterpret_cast<float4*>(out + (size_t)n * kOutF + slice * 16 + lq * 4) = o;
}

extern "C" void kernel_launch(void* const* d_in, const int* in_sizes, int n_in,
                              void* d_out, int out_size, void* d_ws, size_t ws_size,
                              hipStream_t stream) {
    const float* x    = (const float*)d_in[0];
    const int*   erow = (const int*)  d_in[1];
    const int*   ecol = (const int*)  d_in[2];
    const float* eval = (const float*)d_in[3];
    const float* W    = (const float*)d_in[4];
    const float* b    = (const float*)d_in[5];
    float* out = (float*)d_out;

    char* ws = (char*)d_ws;
    unsigned short* support = (unsigned short*)(ws);       // 25,600,000 B (slice-major [8][N][16])
    int2* packed        = (int2*)(ws + 25600000);          // 12,800,000 B
    int*  row_start     = (int*) (ws + 38400000);          //    400,004 B
    int*  bucket_tot    = (int*) (ws + 38800008);          //      1,024 B
    int*  bucket_base   = (int*) (ws + 38801032);          //      1,028 B
    int*  bucket_cursor = (int*) (ws + 38802060);          //      1,024 B

    // 1) support = bf16(x@W + b), slice-major
    gcn_gemm<<<kGemmBlocks, 256, 0, stream>>>(x, W, b, support);

    // 2) CSR build: bucket hist -> bucket scan -> bin -> per-bucket place
    hipMemsetAsync(bucket_tot, 0, kNB * sizeof(int), stream);
    gcn_bhist<<<1024, 256, 0, stream>>>(erow, bucket_tot);
    gcn_bscan<<<1, 256, 0, stream>>>(bucket_tot, bucket_base, bucket_cursor, row_start);
    gcn_bin  <<<kBucketBlocks, 256, 0, stream>>>(erow, ecol, eval, bucket_cursor, packed);
    gcn_place<<<kNB, 256, 0, stream>>>(bucket_base, row_start, packed);

    // 3) aggregate + relu, feature-sliced
    gcn_aggregate<<<kAggTiles * 8, 256, 0, stream>>>(row_start, packed, support, out);
}

// Round 6
// 348.996 us; speedup vs baseline: 1.1694x; 1.1694x over previous
//
#include <hip/hip_runtime.h>

// GCN layer: out = relu(segment_sum(edge_val * (x@W + b)[edge_col] -> edge_row))
// N=100000 nodes, E=1600000 edges, 256 -> 128 features, fp32 in/out.
//
// Round 12: REVERT r11's feature-slicing (aggregate 63->113us: the slice's
// 12.8MB/slice packed stream thrashed the 4MB XCD L2, evicting the 3.2MB
// table it was supposed to keep resident, + 8x packed re-read). Back to
// row-major support [N][128], single-pass aggregate.
// NEW in aggregate: the tile's edges are a contiguous packed run
// [row_start[n0], row_start[n0+16]) -> bulk-stage them into LDS (coalesced,
// independent loads), then the gather loop reads edge records from LDS and
// keeps 8 independent 16B support-gathers in flight per lane (was 4, each
// behind a dependent global packed load). Kills the first hop of the
// packed->gather dependent chain; doubles gather MLP.
// gemm (r9 core, r10 row-major epilogue), bhist/bscan/bin/place (r10)
// unchanged.

constexpr int kNodes = 100000;
constexpr int kEdges = 1600000;
constexpr int kInF   = 256;
constexpr int kOutF  = 128;
constexpr int kTiles = kNodes / 16;                 // 6250
constexpr int kBucketBlocks = 800;                  // 800*256*8 >= E
constexpr int kGemmBlocks = 1250;                   // 5 tiles per block

constexpr int kNB = 256;                            // coarse buckets
constexpr int kRB = 391;                            // rows per bucket (256*391 >= N)
constexpr int kCap = 7424;                          // LDS-staged edges per bucket (58KB)
constexpr int kTileCap = 1024;                      // staged edges per 16-node agg tile (8KB)

typedef __attribute__((ext_vector_type(8))) short short8;
typedef __attribute__((ext_vector_type(8))) unsigned short ush8;
typedef __attribute__((ext_vector_type(4))) float floatx4;

__device__ inline unsigned short f2bf_rne(float f) {
    unsigned int u = __float_as_uint(f);
    unsigned int r = u + 0x7FFFu + ((u >> 16) & 1u);
    return (unsigned short)(r >> 16);
}
__device__ inline float bf2f(unsigned short h) {
    return __uint_as_float(((unsigned int)h) << 16);
}

// 8 fp32 -> 8 bf16 (RNE) via 4x v_cvt_pk_bf16_f32.
__device__ inline short8 cvt8_bf16(const float4 a, const float4 b) {
    union { short8 s; unsigned int u[4]; } r;
    asm("v_cvt_pk_bf16_f32 %0, %1, %2" : "=v"(r.u[0]) : "v"(a.x), "v"(a.y));
    asm("v_cvt_pk_bf16_f32 %0, %1, %2" : "=v"(r.u[1]) : "v"(a.z), "v"(a.w));
    asm("v_cvt_pk_bf16_f32 %0, %1, %2" : "=v"(r.u[2]) : "v"(b.x), "v"(b.y));
    asm("v_cvt_pk_bf16_f32 %0, %1, %2" : "=v"(r.u[3]) : "v"(b.z), "v"(b.w));
    return r.s;
}

// async 16B global->LDS (dest = wave-uniform base + lane*16)
__device__ inline void gload_lds16(const void* g, void* l) {
    __builtin_amdgcn_global_load_lds(
        (const __attribute__((address_space(1))) unsigned int*)g,
        (__attribute__((address_space(3))) unsigned int*)l,
        16, 0, 0);
}

// ---------------------------------------------------------------------------
// GEMM: support_bf[N][128] = bf16(x[N][256] @ W[256][128] + b)  (r9/r10)
// ---------------------------------------------------------------------------
__global__ __launch_bounds__(256) void gcn_gemm(const float* __restrict__ x,
                                                const float* __restrict__ W,
                                                const float* __restrict__ b,
                                                unsigned short* __restrict__ support) {
    __shared__ __align__(16) float lbuf[2][4096];   // 2 x 16KB

    const int lane = threadIdx.x & 63;
    const int wv   = threadIdx.x >> 6;
    const int rowl = lane & 15;
    const int quad = lane >> 4;
    const int colbase = wv * 32;

    short8 bfrag[2][8];
#pragma unroll
    for (int ct = 0; ct < 2; ++ct) {
        const int col = colbase + ct * 16 + rowl;
#pragma unroll
        for (int kc = 0; kc < 8; ++kc) {
            const int kb = kc * 32 + quad * 8;
            short8 f;
#pragma unroll
            for (int j = 0; j < 8; ++j)
                f[j] = (short)f2bf_rne(W[(size_t)(kb + j) * kOutF + col]);
            bfrag[ct][kc] = f;
        }
    }
    const float bias0 = b[colbase + rowl];
    const float bias1 = b[colbase + 16 + rowl];

    const int G = gridDim.x;
    int t = blockIdx.x;

#define GEMM_STAGE(buf_, tile_)                                                   \
    do {                                                                          \
        const float* tb_ = x + (size_t)(tile_) * 16 * kInF;                       \
        _Pragma("unroll")                                                         \
        for (int i_ = 0; i_ < 4; ++i_) {                                          \
            const int row_ = i_ * 4 + wv;                                         \
            gload_lds16(tb_ + (size_t)row_ * kInF + ((lane ^ (row_ & 7)) << 2),   \
                        &lbuf[buf_][row_ << 8]);                                  \
        }                                                                         \
    } while (0)

    if (t < kTiles) GEMM_STAGE(0, t);
    int cur = 0;

    for (; t < kTiles; t += G) {
        const int tn = t + G;
        asm volatile("s_waitcnt vmcnt(0)" ::: "memory");
        __syncthreads();
        if (tn < kTiles) GEMM_STAGE(cur ^ 1, tn);

        const int r0 = t * 16;
        const float* base = &lbuf[cur][rowl << 8];
        const int rsw = rowl & 7;
        floatx4 acc0 = {0.f, 0.f, 0.f, 0.f};
        floatx4 acc1 = {0.f, 0.f, 0.f, 0.f};
#pragma unroll
        for (int kc = 0; kc < 8; ++kc) {
            const int g0 = (kc << 3) + (quad << 1);
            const float4 v0 = *reinterpret_cast<const float4*>(base + ((g0 ^ rsw) << 2));
            const float4 v1 = *reinterpret_cast<const float4*>(base + (((g0 + 1) ^ rsw) << 2));
            const short8 a = cvt8_bf16(v0, v1);
            acc0 = __builtin_amdgcn_mfma_f32_16x16x32_bf16(a, bfrag[0][kc], acc0, 0, 0, 0);
            acc1 = __builtin_amdgcn_mfma_f32_16x16x32_bf16(a, bfrag[1][kc], acc1, 0, 0, 0);
        }
#pragma unroll
        for (int reg = 0; reg < 4; ++reg) {
            const size_t rbase = (size_t)(r0 + quad * 4 + reg) * kOutF + colbase;
            support[rbase + rowl]      = f2bf_rne(acc0[reg] + bias0);
            support[rbase + 16 + rowl] = f2bf_rne(acc1[reg] + bias1);
        }
        cur ^= 1;
    }
#undef GEMM_STAGE
}

// ---------------------------------------------------------------------------
// Bucket histogram: per-block LDS hist over 256 buckets. (r10, unchanged)
// ---------------------------------------------------------------------------
__global__ __launch_bounds__(256) void gcn_bhist(const int* __restrict__ erow,
                                                 int* __restrict__ bucket_tot) {
    __shared__ int cnt[kNB];
    cnt[threadIdx.x] = 0;
    __syncthreads();
    const int stride = gridDim.x * blockDim.x;
    for (int e = blockIdx.x * blockDim.x + threadIdx.x; e < kEdges; e += stride)
        atomicAdd(&cnt[(unsigned int)erow[e] / (unsigned int)kRB], 1);
    __syncthreads();
    const int c = cnt[threadIdx.x];
    if (c) atomicAdd(&bucket_tot[threadIdx.x], c);
}

// ---------------------------------------------------------------------------
// Bucket scan: one block, exclusive scan of 256 totals. (r10, unchanged)
// ---------------------------------------------------------------------------
__global__ __launch_bounds__(256) void gcn_bscan(const int* __restrict__ bucket_tot,
                                                 int* __restrict__ bucket_base,
                                                 int* __restrict__ bucket_cursor,
                                                 int* __restrict__ row_start) {
    __shared__ int s[256];
    const int v = bucket_tot[threadIdx.x];
    s[threadIdx.x] = v;
    __syncthreads();
#pragma unroll
    for (int off = 1; off < 256; off <<= 1) {
        const int t = (threadIdx.x >= off) ? s[threadIdx.x - off] : 0;
        __syncthreads();
        s[threadIdx.x] += t;
        __syncthreads();
    }
    const int excl = s[threadIdx.x] - v;
    bucket_base[threadIdx.x]   = excl;
    bucket_cursor[threadIdx.x] = excl;
    if (threadIdx.x == 255) {
        bucket_base[256]   = kEdges;
        row_start[kNodes]  = kEdges;
    }
}

// ---------------------------------------------------------------------------
// Phase A: bin edges into 256 coarse buckets, write-combined. (unchanged)
// packed.x = (row_local<<17) | col. packed.y = val.
// ---------------------------------------------------------------------------
__global__ __launch_bounds__(256) void gcn_bin(const int* __restrict__ erow,
                                               const int* __restrict__ ecol,
                                               const float* __restrict__ eval,
                                               int* __restrict__ bucket_cursor,
                                               int2* __restrict__ packed) {
    __shared__ int cnt[kNB];
    __shared__ int base[kNB];
    __shared__ int rk[kNB];
    const int T   = kBucketBlocks * 256;
    const int tid = blockIdx.x * 256 + threadIdx.x;

    cnt[threadIdx.x] = 0;
    rk[threadIdx.x]  = 0;

    int bk[8], pk[8], vb[8];
    bool ok[8];
#pragma unroll
    for (int i = 0; i < 8; ++i) {
        const int e = tid + i * T;
        ok[i] = (e < kEdges);
        const int r = ok[i] ? erow[e] : 0;
        const int c = ok[i] ? ecol[e] : 0;
        const float v = ok[i] ? eval[e] : 0.f;
        const unsigned int b = (unsigned int)r / (unsigned int)kRB;
        bk[i] = (int)b;
        pk[i] = ((r - (int)b * kRB) << 17) | c;
        vb[i] = __float_as_int(v);
    }
    __syncthreads();
#pragma unroll
    for (int i = 0; i < 8; ++i)
        if (ok[i]) atomicAdd(&cnt[bk[i]], 1);
    __syncthreads();
    const int c = cnt[threadIdx.x];
    base[threadIdx.x] = c ? atomicAdd(&bucket_cursor[threadIdx.x], c) : 0;
    __syncthreads();
#pragma unroll
    for (int i = 0; i < 8; ++i) {
        if (ok[i]) {
            const int r = atomicAdd(&rk[bk[i]], 1);
            packed[base[bk[i]] + r] = make_int2(pk[i], vb[i]);
        }
    }
}

// ---------------------------------------------------------------------------
// Phase B: per-bucket place, all bookkeeping in LDS. (r10, unchanged)
// ---------------------------------------------------------------------------
__global__ __launch_bounds__(256) void gcn_place(const int* __restrict__ bucket_base,
                                                 int* __restrict__ row_start,
                                                 int2* __restrict__ packed) {
    __shared__ int2 st[kCap];       // 59,392 B
    __shared__ int  s[512];         //  2,048 B
    __shared__ int  rcur[kRB + 1];  //  1,568 B
    const int bk = blockIdx.x;
    const int r0 = bk * kRB;
    const int r1 = min(r0 + kRB, kNodes);
    const int NR = r1 - r0;
    if (NR <= 0) return;
    const int bb = bucket_base[bk];
    const int s1 = bucket_base[bk + 1];
    const int size   = s1 - bb;
    const int staged = min(size, kCap);
    const int tid = threadIdx.x;

    s[tid] = 0;
    s[tid + 256] = 0;
    __syncthreads();

    for (int i = tid; i < staged; i += 256) {
        const int2 p = packed[bb + i];
        st[i] = p;
        atomicAdd(&s[p.x >> 17], 1);
    }
    int2 tail[8];
    int  nt = 0;
    for (int i = kCap + tid; i < size; i += 256) {
        if (nt < 8) {
            tail[nt] = packed[bb + i];
            atomicAdd(&s[tail[nt].x >> 17], 1);
            ++nt;
        }
    }
    __syncthreads();

    const int i0 = tid, i1 = tid + 256;
#pragma unroll
    for (int off = 1; off < 512; off <<= 1) {
        const int v0 = (i0 >= off) ? s[i0 - off] : 0;
        const int v1 = (i1 >= off) ? s[i1 - off] : 0;
        __syncthreads();
        s[i0] += v0;
        s[i1] += v1;
        __syncthreads();
    }

    for (int i = tid; i < NR; i += 256) {
        const int excl = i ? s[i - 1] : 0;
        row_start[r0 + i] = bb + excl;
        rcur[i] = excl;
    }
    __syncthreads();

    for (int i = tid; i < staged; i += 256) {
        const int2 p  = st[i];
        const int pos = bb + atomicAdd(&rcur[p.x >> 17], 1);
        packed[pos] = make_int2(p.x & 0x1FFFF, p.y);
    }
#pragma unroll
    for (int t = 0; t < 8; ++t) {
        if (t < nt) {
            const int2 p  = tail[t];
            const int pos = bb + atomicAdd(&rcur[p.x >> 17], 1);
            packed[pos] = make_int2(p.x & 0x1FFFF, p.y);
        }
    }
}

// ---------------------------------------------------------------------------
// Aggregate + ReLU: 16 nodes x 16 lanes per block. The tile's edges are a
// contiguous packed run -> bulk-stage into LDS (coalesced, independent),
// then per-node gather loop reads edge records from LDS and keeps 8
// independent 16B support-gathers in flight per lane. Fallback to direct
// global packed reads if a tile exceeds kTileCap edges (Poisson(256) ->
// never in practice, but correctness doesn't depend on that).
// ---------------------------------------------------------------------------
__global__ __launch_bounds__(256) void gcn_aggregate(const int* __restrict__ row_start,
                                                     const int2* __restrict__ packed,
                                                     const unsigned short* __restrict__ support,
                                                     float* __restrict__ out) {
    __shared__ int2 ep[kTileCap];
    const int n0 = blockIdx.x * 16;
    const int e0 = row_start[n0];
    const int eN = row_start[n0 + 16] - e0;
    const int nStage = min(eN, kTileCap);
    for (int i = threadIdx.x; i < nStage; i += 256)
        ep[i] = packed[e0 + i];
    __syncthreads();

    const int n  = n0 + (threadIdx.x >> 4);
    const int f8 = (threadIdx.x & 15) * 8;
    const unsigned short* sb = support + f8;
    const int s0 = row_start[n]     - e0;
    const int s1 = row_start[n + 1] - e0;

    float acc[8];
#pragma unroll
    for (int j = 0; j < 8; ++j) acc[j] = 0.f;

    if (eN <= kTileCap) {
        // fast path: all edge records in LDS; 8 gathers in flight
        int i = s0;
        for (; i + 7 < s1; i += 8) {
            int2 p[8];
#pragma unroll
            for (int k = 0; k < 8; ++k) p[k] = ep[i + k];
            ush8 g[8];
#pragma unroll
            for (int k = 0; k < 8; ++k)
                g[k] = *reinterpret_cast<const ush8*>(sb + (size_t)p[k].x * kOutF);
#pragma unroll
            for (int k = 0; k < 8; ++k) {
                const float v = __int_as_float(p[k].y);
#pragma unroll
                for (int j = 0; j < 8; ++j) acc[j] += v * bf2f(g[k][j]);
            }
        }
        for (; i < s1; ++i) {
            const int2 p = ep[i];
            const float v = __int_as_float(p.y);
            const ush8 g = *reinterpret_cast<const ush8*>(sb + (size_t)p.x * kOutF);
#pragma unroll
            for (int j = 0; j < 8; ++j) acc[j] += v * bf2f(g[j]);
        }
    } else {
        // fallback: direct global reads (r10 structure)
        int i = s0;
        for (; i + 3 < s1; i += 4) {
            const int2 p0 = packed[e0 + i];
            const int2 p1 = packed[e0 + i + 1];
            const int2 p2 = packed[e0 + i + 2];
            const int2 p3 = packed[e0 + i + 3];
            const ush8 a0 = *reinterpret_cast<const ush8*>(sb + (size_t)p0.x * kOutF);
            const ush8 a1 = *reinterpret_cast<const ush8*>(sb + (size_t)p1.x * kOutF);
            const ush8 a2 = *reinterpret_cast<const ush8*>(sb + (size_t)p2.x * kOutF);
            const ush8 a3 = *reinterpret_cast<const ush8*>(sb + (size_t)p3.x * kOutF);
            const float v0 = __int_as_float(p0.y), v1 = __int_as_float(p1.y);
            const float v2 = __int_as_float(p2.y), v3 = __int_as_float(p3.y);
#pragma unroll
            for (int j = 0; j < 8; ++j) {
                acc[j] += v0 * bf2f(a0[j]);
                acc[j] += v1 * bf2f(a1[j]);
                acc[j] += v2 * bf2f(a2[j]);
                acc[j] += v3 * bf2f(a3[j]);
            }
        }
        for (; i < s1; ++i) {
            const int2 p = packed[e0 + i];
            const float v = __int_as_float(p.y);
            const ush8 a = *reinterpret_cast<const ush8*>(sb + (size_t)p.x * kOutF);
#pragma unroll
            for (int j = 0; j < 8; ++j) acc[j] += v * bf2f(a[j]);
        }
    }

    float4 o0 = make_float4(fmaxf(acc[0], 0.f), fmaxf(acc[1], 0.f),
                            fmaxf(acc[2], 0.f), fmaxf(acc[3], 0.f));
    float4 o1 = make_float4(fmaxf(acc[4], 0.f), fmaxf(acc[5], 0.f),
                            fmaxf(acc[6], 0.f), fmaxf(acc[7], 0.f));
    *reinterpret_cast<float4*>(out + (size_t)n * kOutF + f8)     = o0;
    *reinterpret_cast<float4*>(out + (size_t)n * kOutF + f8 + 4) = o1;
}

extern "C" void kernel_launch(void* const* d_in, const int* in_sizes, int n_in,
                              void* d_out, int out_size, void* d_ws, size_t ws_size,
                              hipStream_t stream) {
    const float* x    = (const float*)d_in[0];
    const int*   erow = (const int*)  d_in[1];
    const int*   ecol = (const int*)  d_in[2];
    const float* eval = (const float*)d_in[3];
    const float* W    = (const float*)d_in[4];
    const float* b    = (const float*)d_in[5];
    float* out = (float*)d_out;

    char* ws = (char*)d_ws;
    unsigned short* support = (unsigned short*)(ws);       // 25,600,000 B (row-major [N][128])
    int2* packed        = (int2*)(ws + 25600000);          // 12,800,000 B
    int*  row_start     = (int*) (ws + 38400000);          //    400,004 B
    int*  bucket_tot    = (int*) (ws + 38800008);          //      1,024 B
    int*  bucket_base   = (int*) (ws + 38801032);          //      1,028 B
    int*  bucket_cursor = (int*) (ws + 38802060);          //      1,024 B

    // 1) support = bf16(x@W + b)
    gcn_gemm<<<kGemmBlocks, 256, 0, stream>>>(x, W, b, support);

    // 2) CSR build: bucket hist -> bucket scan -> bin -> per-bucket place
    hipMemsetAsync(bucket_tot, 0, kNB * sizeof(int), stream);
    gcn_bhist<<<1024, 256, 0, stream>>>(erow, bucket_tot);
    gcn_bscan<<<1, 256, 0, stream>>>(bucket_tot, bucket_base, bucket_cursor, row_start);
    gcn_bin  <<<kBucketBlocks, 256, 0, stream>>>(erow, ecol, eval, bucket_cursor, packed);
    gcn_place<<<kNB, 256, 0, stream>>>(bucket_base, row_start, packed);

    // 3) aggregate + relu (LDS-staged edge records, 8-deep gather pipeline)
    gcn_aggregate<<<kTiles, 256, 0, stream>>>(row_start, packed, support, out);
}